// Round 16
// baseline (85.777 us; speedup 1.0000x reference)
//
#include <hip/hip_runtime.h>
#include <hip/hip_fp16.h>

// Problem constants
#define NB   8
#define NC   256
#define HW   56
#define NPX  3136          // 56*56
#define RED  64
#define NG   16
#define GC   16
#define KS   7
#define KK   49
#define PADK 3
#define XPH  62            // padded rows: 3 + 56 + 3
#define XPW  64            // padded row stride (elements)
#define XPSLICE (XPH * XPW)   // 3968 f16 per channel slice
// K2b tiling
#define TPX  224           // px tile = 4 full pixel rows
#define NT2  14            // 3136 / 224
#define XT2_CS 644         // xtap ch stride (f16): 10*64+4 -> bank spread

typedef float f32x4 __attribute__((ext_vector_type(4)));
typedef _Float16 h16x4 __attribute__((ext_vector_type(4)));
typedef _Float16 h16x8 __attribute__((ext_vector_type(8)));

// ---------------------------------------------------------------------------
// K0: fused prep.  blocks 0..2047: pad+convert x -> xpad f16 (incl. border);
//     blocks 2048..2063: w2 -> w2h f16; block 2064: w1 -> w1h.
// ---------------------------------------------------------------------------
__global__ __launch_bounds__(256) void prep_kernel(
    const float* __restrict__ x, const float* __restrict__ w1,
    const float* __restrict__ w2, _Float16* __restrict__ xpad,
    _Float16* __restrict__ w1h, _Float16* __restrict__ w2h) {
    int bid = blockIdx.x;
    if (bid < NB * NC) {
        const float* xs = x + (size_t)bid * NPX;
        _Float16* xd = xpad + (size_t)bid * XPSLICE;
#pragma unroll 4
        for (int e = threadIdx.x; e < XPSLICE; e += 256) {
            int row = e >> 6, col = e & 63;
            int h = row - PADK, w = col - PADK;
            float v = (h >= 0 && h < HW && w >= 0 && w < HW) ? xs[h * HW + w] : 0.0f;
            xd[e] = (_Float16)v;
        }
    } else if (bid < NB * NC + NG) {
        int g = bid - NB * NC;
#pragma unroll 4
        for (int e = threadIdx.x; e < 4096; e += 256) {
            int m = e >> 6, k = e & 63;
            float v = (m < KK) ? w2[((size_t)g * KK + m) * RED + k] : 0.0f;
            w2h[(size_t)g * 4096 + e] = (_Float16)v;
        }
    } else {
#pragma unroll 4
        for (int e = threadIdx.x; e < 64 * 256; e += 256)
            w1h[e] = (_Float16)w1[e];
    }
}

// ---------------------------------------------------------------------------
// K1: conv1 via MFMA f16 (r12/r15 version, 1 wave/block).
// Grid 1568 (8b x 196 nt; b = wgid&7), 64 thr. Wave computes C[64 o][16 px].
// ---------------------------------------------------------------------------
__global__ __launch_bounds__(64) void conv1_kernel(
    const _Float16* __restrict__ xpad, const _Float16* __restrict__ w1h,
    const float* __restrict__ g1, const float* __restrict__ be1,
    const float* __restrict__ mu1, const float* __restrict__ var1,
    _Float16* __restrict__ tT) {
    int lane = threadIdx.x;
    int l15 = lane & 15, l4 = lane >> 4;
    int wgid = blockIdx.x;                 // 1568 = 8 * 196
    int b  = wgid & 7;                     // XCD-local batch
    int nt = wgid >> 3;                    // 0..195
    int px = nt * 16 + l15;
    int h = px / HW, w = px % HW;

    const _Float16* xp = xpad + (size_t)b * NC * XPSLICE
                       + (h + PADK) * XPW + (w + PADK);

    f32x4 acc0 = {0,0,0,0}, acc1 = {0,0,0,0}, acc2 = {0,0,0,0}, acc3 = {0,0,0,0};
#pragma unroll
    for (int kk = 0; kk < 8; ++kk) {
        h16x8 bfr;
#pragma unroll
        for (int i = 0; i < 8; ++i)
            bfr[i] = xp[(size_t)(kk * 32 + l4 * 8 + i) * XPSLICE];
#pragma unroll
        for (int mt = 0; mt < 4; ++mt) {
            const _Float16* ap = w1h + (mt * 16 + l15) * NC + kk * 32 + l4 * 8;
            h16x8 a = *(const h16x8*)ap;
            f32x4 c = (mt == 0) ? acc0 : (mt == 1) ? acc1 : (mt == 2) ? acc2 : acc3;
            c = __builtin_amdgcn_mfma_f32_16x16x32_f16(a, bfr, c, 0, 0, 0);
            if (mt == 0) acc0 = c; else if (mt == 1) acc1 = c;
            else if (mt == 2) acc2 = c; else acc3 = c;
        }
    }

    _Float16* tb = tT + ((size_t)b * NPX + px) * RED;
#pragma unroll
    for (int mt = 0; mt < 4; ++mt) {
        f32x4 a = (mt == 0) ? acc0 : (mt == 1) ? acc1 : (mt == 2) ? acc2 : acc3;
        int o0 = mt * 16 + l4 * 4;
        h16x4 pk;
#pragma unroll
        for (int r = 0; r < 4; ++r) {
            int o = o0 + r;
            float inv = g1[o] * rsqrtf(var1[o] + 1e-5f);
            float v = a[r] * inv + (be1[o] - mu1[o] * inv);
            pk[r] = (_Float16)fmaxf(v, 0.0f);
        }
        *(h16x4*)(tb + o0) = pk;
    }
}

// ---------------------------------------------------------------------------
// K2a: conv2 GEMM only.  wgt[b][g][k][px] f16 = w2h . tT + b2.
// Grid 6272 (XCD-swizzled 8x784: b = XCD), 256 thr = 4 waves; wave wv = N-tile
// wv of a 64-px macro-tile: 8 MFMAs. C -> LDS transpose -> coalesced b128
// global stores (49 rows x 128 B).
// ---------------------------------------------------------------------------
__global__ __launch_bounds__(256) void conv2_kernel(
    const _Float16* __restrict__ tT, const _Float16* __restrict__ w2h,
    const float* __restrict__ b2, _Float16* __restrict__ wgt) {
    __shared__ __align__(16) _Float16 wls[KK * 64];    // 6272 B

    int tid  = threadIdx.x;
    int lane = tid & 63;
    int wv   = __builtin_amdgcn_readfirstlane(tid >> 6);   // 0..3 SGPR
    int wgid = blockIdx.x;                 // 6272 = 8 * 784
    int swz  = (wgid & 7) * 784 + (wgid >> 3);
    int tile = swz % 49;
    int g    = (swz / 49) & 15;
    int b    = swz / 784;
    int px0 = tile * 64;

    int l15 = lane & 15, l4 = lane >> 4;
    int pxc = px0 + wv * 16 + l15;
    const _Float16* tp = tT + ((size_t)b * NPX + pxc) * RED + l4 * 8;
    h16x8 bfr0 = *(const h16x8*)tp;
    h16x8 bfr1 = *(const h16x8*)(tp + 32);

    const _Float16* wA = w2h + (size_t)g * 4096;
    const float* bg = b2 + (size_t)g * KK;
    f32x4 acc0 = {0,0,0,0}, acc1 = {0,0,0,0}, acc2 = {0,0,0,0}, acc3 = {0,0,0,0};
#pragma unroll
    for (int mt = 0; mt < 4; ++mt) {
        const _Float16* ap = wA + (mt * 16 + l15) * 64 + l4 * 8;
        h16x8 a0 = *(const h16x8*)(ap);
        h16x8 a1 = *(const h16x8*)(ap + 32);
        f32x4 a = (mt == 0) ? acc0 : (mt == 1) ? acc1 : (mt == 2) ? acc2 : acc3;
        a = __builtin_amdgcn_mfma_f32_16x16x32_f16(a0, bfr0, a, 0, 0, 0);
        a = __builtin_amdgcn_mfma_f32_16x16x32_f16(a1, bfr1, a, 0, 0, 0);
        if (mt == 0) acc0 = a; else if (mt == 1) acc1 = a;
        else if (mt == 2) acc2 = a; else acc3 = a;
    }
    _Float16* wl = wls + wv * 16 + l15;
#pragma unroll
    for (int mt = 0; mt < 4; ++mt) {
        f32x4 a = (mt == 0) ? acc0 : (mt == 1) ? acc1 : (mt == 2) ? acc2 : acc3;
#pragma unroll
        for (int r = 0; r < 4; ++r) {
            int k = mt * 16 + l4 * 4 + r;
            if (k < KK) wl[k * 64] = (_Float16)(a[r] + bg[k]);
        }
    }
    __syncthreads();

    // coalesced store: 392 chunks of 16 B (49 k-rows x 8)
    _Float16* wg_ = wgt + ((size_t)(b * NG + g) * KK) * NPX + px0;
#pragma unroll
    for (int u = 0; u < 2; ++u) {
        int cid = u * 256 + tid;
        if (cid < 392) {
            int k = cid >> 3, c8 = cid & 7;
            *(h16x8*)(wg_ + (size_t)k * NPX + c8 * 8) =
                *(const h16x8*)&wls[k * 64 + c8 * 8];
        }
    }
}

// ---------------------------------------------------------------------------
// K2b: pure stencil: out = relu(bn2(sum_k wgt[k] * xpad_tap[k])).
// Grid 1792 (XCD-swizzled 8x224: b = XCD), 448 thr = 7 waves.
// LDS: xtap only (20.6 KB) -> ~4 blocks/CU = 28 waves/CU.
// Thread = (octet, ch): 8 px x 1 ch. Per i: 7 global b128 wq loads (16-way
// lane-broadcast, L2-hot, independent -> MLP), 2 LDS b128 taps, 56 FMA.
// ---------------------------------------------------------------------------
__global__ __launch_bounds__(448) void stencil_kernel(
    const _Float16* __restrict__ xpad, const _Float16* __restrict__ wgt,
    const float* __restrict__ g2, const float* __restrict__ be2,
    const float* __restrict__ mu2, const float* __restrict__ var2,
    float* __restrict__ out) {
    __shared__ __align__(16) _Float16 xtap[GC * XT2_CS];  // 20,608 B

    int tid  = threadIdx.x;
    int wgid = blockIdx.x;                 // 1792 = 8 * 224
    int swz  = (wgid & 7) * 224 + (wgid >> 3);
    int b    = swz / 224;
    int rem  = swz % 224;
    int g    = rem / NT2;                  // 0..15
    int tile = rem % NT2;                  // 0..13
    int px0 = tile * TPX;
    int R0  = tile * 4;

    const _Float16* xpg = xpad + ((size_t)b * NC + (size_t)g * GC) * XPSLICE;

    // stage xtap: 16ch x 10rows x 64col = 1280 16B-chunks
#pragma unroll
    for (int u = 0; u < 3; ++u) {
        int cid = u * 448 + tid;
        if (cid < 1280) {
            int ch = cid / 80;
            int rm = cid % 80;
            int rr = rm >> 3, c8 = rm & 7;
            *(h16x8*)&xtap[ch * XT2_CS + rr * 64 + c8 * 8] =
                *(const h16x8*)(xpg + (size_t)ch * XPSLICE + (R0 + rr) * XPW + c8 * 8);
        }
    }
    __syncthreads();

    int octet = tid >> 4;                  // 0..27
    int ch    = tid & 15;                  // 0..15
    int lin   = octet * 8;                 // 0..216
    int lh    = lin / 56;                  // 0..3
    int w0    = lin % 56;                  // multiple of 8

    const _Float16* xb0 = xtap + ch * XT2_CS + lh * 64 + w0;
    const _Float16* wq0 = wgt + ((size_t)(b * NG + g) * KK) * NPX + px0 + lin;

    float acc[8];
#pragma unroll
    for (int p = 0; p < 8; ++p) acc[p] = 0.0f;

#pragma unroll
    for (int i = 0; i < KS; ++i) {
        // issue all 7 wq loads for this tap row (independent, L2-hot)
        h16x8 wq7[KS];
#pragma unroll
        for (int j = 0; j < KS; ++j)
            wq7[j] = *(const h16x8*)(wq0 + (size_t)(i * KS + j) * NPX);
        h16x8 t0 = *(const h16x8*)(xb0 + i * 64);       // cols w0..w0+7
        h16x8 t1 = *(const h16x8*)(xb0 + i * 64 + 8);   // cols w0+8..+15
        float cc[16];
#pragma unroll
        for (int p = 0; p < 8; ++p) { cc[p] = (float)t0[p]; cc[8 + p] = (float)t1[p]; }
#pragma unroll
        for (int j = 0; j < KS; ++j) {
#pragma unroll
            for (int p = 0; p < 8; ++p)
                acc[p] = fmaf((float)wq7[j][p], cc[j + p], acc[p]);
        }
    }

    int c_ = g * GC + ch;
    float inv = g2[c_] * rsqrtf(var2[c_] + 1e-5f);
    float off = be2[c_] - mu2[c_] * inv;
    float* op = out + ((size_t)b * NC + c_) * NPX + px0 + lin;
    f32x4 o0, o1;
#pragma unroll
    for (int p = 0; p < 4; ++p) {
        o0[p] = fmaxf(acc[p] * inv + off, 0.0f);
        o1[p] = fmaxf(acc[4 + p] * inv + off, 0.0f);
    }
    *(f32x4*)(op)     = o0;
    *(f32x4*)(op + 4) = o1;
}

// ---------------------------------------------------------------------------
extern "C" void kernel_launch(void* const* d_in, const int* in_sizes, int n_in,
                              void* d_out, int out_size, void* d_ws, size_t ws_size,
                              hipStream_t stream) {
    const float* x    = (const float*)d_in[0];
    const float* w1   = (const float*)d_in[1];
    const float* g1   = (const float*)d_in[2];
    const float* be1  = (const float*)d_in[3];
    const float* mu1  = (const float*)d_in[4];
    const float* var1 = (const float*)d_in[5];
    const float* w2   = (const float*)d_in[6];
    const float* b2   = (const float*)d_in[7];
    const float* g2   = (const float*)d_in[8];
    const float* be2  = (const float*)d_in[9];
    const float* mu2  = (const float*)d_in[10];
    const float* var2 = (const float*)d_in[11];
    float* outp = (float*)d_out;

    // ws: xpad f16 16.3MB | tT f16 3.2MB | wgt f16 39.3MB | w2h 128KB | w1h 32KB
    _Float16* xpad = (_Float16*)d_ws;
    _Float16* tT   = xpad + (size_t)NB * NC * XPSLICE;
    _Float16* wgt  = tT + (size_t)NB * NPX * RED;
    _Float16* w2h  = wgt + (size_t)NB * NG * KK * NPX;
    _Float16* w1h  = w2h + (size_t)NG * 4096;

    prep_kernel<<<NB * NC + NG + 1, 256, 0, stream>>>(x, w1, w2, xpad, w1h, w2h);
    conv1_kernel<<<1568, 64, 0, stream>>>(xpad, w1h, g1, be1, mu1, var1, tT);
    conv2_kernel<<<6272, 256, 0, stream>>>(tT, w2h, b2, wgt);
    stencil_kernel<<<1792, 448, 0, stream>>>(
        xpad, wgt, g2, be2, mu2, var2, outp);
}

// Round 17
// 75.083 us; speedup vs baseline: 1.1424x; 1.1424x over previous
//
#include <hip/hip_runtime.h>
#include <hip/hip_fp16.h>

// Problem constants
#define NB   8
#define NC   256
#define HW   56
#define NPX  3136          // 56*56
#define RED  64
#define NG   16
#define GC   16
#define KS   7
#define KK   49
#define PADK 3
#define XPH  62            // padded rows: 3 + 56 + 3
#define XPW  64            // padded row stride (elements)
#define XPSLICE (XPH * XPW)   // 3968 f16 per channel slice
#define XT_RS 72           // xtap row stride (f16): 144 B
#define XT_CS 584          // xtap ch stride (f16)
#define WSTR  68           // wls px stride (f16)

typedef float f32x4 __attribute__((ext_vector_type(4)));
typedef _Float16 h16x4 __attribute__((ext_vector_type(4)));
typedef _Float16 h16x8 __attribute__((ext_vector_type(8)));

// ---------------------------------------------------------------------------
// K0: fused prep.  blocks 0..2047: pad+convert x -> xpad f16 (incl. border);
//     blocks 2048..2063: w2 -> w2h f16; block 2064: w1 -> w1h.
// ---------------------------------------------------------------------------
__global__ __launch_bounds__(256) void prep_kernel(
    const float* __restrict__ x, const float* __restrict__ w1,
    const float* __restrict__ w2, _Float16* __restrict__ xpad,
    _Float16* __restrict__ w1h, _Float16* __restrict__ w2h) {
    int bid = blockIdx.x;
    if (bid < NB * NC) {
        const float* xs = x + (size_t)bid * NPX;
        _Float16* xd = xpad + (size_t)bid * XPSLICE;
#pragma unroll 4
        for (int e = threadIdx.x; e < XPSLICE; e += 256) {
            int row = e >> 6, col = e & 63;
            int h = row - PADK, w = col - PADK;
            float v = (h >= 0 && h < HW && w >= 0 && w < HW) ? xs[h * HW + w] : 0.0f;
            xd[e] = (_Float16)v;
        }
    } else if (bid < NB * NC + NG) {
        int g = bid - NB * NC;
#pragma unroll 4
        for (int e = threadIdx.x; e < 4096; e += 256) {
            int m = e >> 6, k = e & 63;
            float v = (m < KK) ? w2[((size_t)g * KK + m) * RED + k] : 0.0f;
            w2h[(size_t)g * 4096 + e] = (_Float16)v;
        }
    } else {
#pragma unroll 4
        for (int e = threadIdx.x; e < 64 * 256; e += 256)
            w1h[e] = (_Float16)w1[e];
    }
}

// ---------------------------------------------------------------------------
// K1: conv1 via MFMA f16 (r12/r15 version, 1 wave/block).
// Grid 1568 (8b x 196 nt; b = wgid&7), 64 thr. Wave computes C[64 o][16 px].
// ---------------------------------------------------------------------------
__global__ __launch_bounds__(64) void conv1_kernel(
    const _Float16* __restrict__ xpad, const _Float16* __restrict__ w1h,
    const float* __restrict__ g1, const float* __restrict__ be1,
    const float* __restrict__ mu1, const float* __restrict__ var1,
    _Float16* __restrict__ tT) {
    int lane = threadIdx.x;
    int l15 = lane & 15, l4 = lane >> 4;
    int wgid = blockIdx.x;                 // 1568 = 8 * 196
    int b  = wgid & 7;                     // XCD-local batch
    int nt = wgid >> 3;                    // 0..195
    int px = nt * 16 + l15;
    int h = px / HW, w = px % HW;

    const _Float16* xp = xpad + (size_t)b * NC * XPSLICE
                       + (h + PADK) * XPW + (w + PADK);

    f32x4 acc0 = {0,0,0,0}, acc1 = {0,0,0,0}, acc2 = {0,0,0,0}, acc3 = {0,0,0,0};
#pragma unroll
    for (int kk = 0; kk < 8; ++kk) {
        h16x8 bfr;
#pragma unroll
        for (int i = 0; i < 8; ++i)
            bfr[i] = xp[(size_t)(kk * 32 + l4 * 8 + i) * XPSLICE];
#pragma unroll
        for (int mt = 0; mt < 4; ++mt) {
            const _Float16* ap = w1h + (mt * 16 + l15) * NC + kk * 32 + l4 * 8;
            h16x8 a = *(const h16x8*)ap;
            f32x4 c = (mt == 0) ? acc0 : (mt == 1) ? acc1 : (mt == 2) ? acc2 : acc3;
            c = __builtin_amdgcn_mfma_f32_16x16x32_f16(a, bfr, c, 0, 0, 0);
            if (mt == 0) acc0 = c; else if (mt == 1) acc1 = c;
            else if (mt == 2) acc2 = c; else acc3 = c;
        }
    }

    _Float16* tb = tT + ((size_t)b * NPX + px) * RED;
#pragma unroll
    for (int mt = 0; mt < 4; ++mt) {
        f32x4 a = (mt == 0) ? acc0 : (mt == 1) ? acc1 : (mt == 2) ? acc2 : acc3;
        int o0 = mt * 16 + l4 * 4;
        h16x4 pk;
#pragma unroll
        for (int r = 0; r < 4; ++r) {
            int o = o0 + r;
            float inv = g1[o] * rsqrtf(var1[o] + 1e-5f);
            float v = a[r] * inv + (be1[o] - mu1[o] * inv);
            pk[r] = (_Float16)fmaxf(v, 0.0f);
        }
        *(h16x4*)(tb + o0) = pk;
    }
}

// ---------------------------------------------------------------------------
// K2: fused conv2(MFMA f16) -> involution -> bn2 -> relu, PERSISTENT blocks.
// Grid 1568 (b = wgid&7 -> XCD-local), 256 thr (4 waves). Each block runs 4
// (g,tile) units of the r12 geometry with cross-unit register prefetch:
//   B1(lgkm-only barrier) -> xtap regs->LDS -> phase A MFMA (prefetched tT
//   frags) -> bn2 params -> ISSUE next unit's xtap+tT loads -> B2(lgkm-only
//   barrier) -> phase B (no VMEM -> prefetch stays in flight).
// Raw s_barrier + lgkmcnt(0) (NOT __syncthreads) so the vmcnt(0) drain never
// kills the cross-unit prefetch (m97 lesson). LDS 25.4 KB single-buffered.
// ---------------------------------------------------------------------------
__global__ __launch_bounds__(256) void involution_kernel(
    const _Float16* __restrict__ xpad, const _Float16* __restrict__ tT,
    const _Float16* __restrict__ w2h, const float* __restrict__ b2,
    const float* __restrict__ g2v, const float* __restrict__ be2,
    const float* __restrict__ mu2, const float* __restrict__ var2,
    float* __restrict__ out) {
    __shared__ __align__(16) _Float16 xtap[GC * XT_CS];  // 18,688 B
    __shared__ __align__(16) _Float16 wls[KK * WSTR];    //  6,664 B

    int tid  = threadIdx.x;
    int lane = tid & 63;
    int wv   = __builtin_amdgcn_readfirstlane(tid >> 6);   // 0..3 SGPR
    int l15 = lane & 15, l4 = lane >> 4;
    int quad = tid & 15;                   // phase-B px-quad
    int chB  = tid >> 4;                   // phase-B channel
    int bid = blockIdx.x;                  // 1568 = 8 * 196
    int b   = bid & 7;                     // XCD-local batch
    int idx = bid >> 3;                    // 0..195 -> units idx*4..idx*4+3

    h16x8 xrP[2][4];                       // double-buffered staging regs
    h16x8 bfP[2][2];                       // double-buffered tT B-frags

    // ---- prologue: issue unit-0 loads ----
    {
        int un = idx * 4;
        int g = un / 49, tile = un % 49;
        int px0 = tile * 64, h0 = px0 / HW;
        const _Float16* xpg = xpad + ((size_t)b * NC + (size_t)g * GC) * XPSLICE;
#pragma unroll
        for (int su = 0; su < 4; ++su) {
            int c_ = su * 256 + tid;
            int ch = c_ >> 6, rem = c_ & 63, rr = rem >> 3, c8 = rem & 7;
            xrP[0][su] = *(const h16x8*)(xpg + (size_t)ch * XPSLICE
                                         + (h0 + rr) * XPW + c8 * 8);
        }
        int pxc = px0 + wv * 16 + l15;
        const _Float16* tp = tT + ((size_t)b * NPX + pxc) * RED + l4 * 8;
        bfP[0][0] = *(const h16x8*)tp;
        bfP[0][1] = *(const h16x8*)(tp + 32);
    }

#pragma unroll
    for (int u = 0; u < 4; ++u) {
        const int cur = u & 1;             // compile-time under full unroll
        const int nxt = cur ^ 1;
        int un = idx * 4 + u;
        int g = un / 49, tile = un % 49;
        int px0 = tile * 64, h0 = px0 / HW;

        // ---- B1: previous unit's phase-B LDS reads are done ----
        asm volatile("s_waitcnt lgkmcnt(0)" ::: "memory");
        __builtin_amdgcn_s_barrier();
        __builtin_amdgcn_sched_barrier(0);

        // ---- staged regs -> xtap LDS ----
#pragma unroll
        for (int su = 0; su < 4; ++su) {
            int c_ = su * 256 + tid;
            int ch = c_ >> 6, rem = c_ & 63, rr = rem >> 3, c8 = rem & 7;
            *(h16x8*)&xtap[ch * XT_CS + rr * XT_RS + c8 * 8] = xrP[cur][su];
        }

        // ---- phase A: MFMA wgt = w2h[g] . tT-frags (prefetched) ----
        {
            const _Float16* wA = w2h + (size_t)g * 4096;
            const float* bg = b2 + (size_t)g * KK;
            f32x4 acc0 = {0,0,0,0}, acc1 = {0,0,0,0},
                  acc2 = {0,0,0,0}, acc3 = {0,0,0,0};
#pragma unroll
            for (int mt = 0; mt < 4; ++mt) {
                const _Float16* ap = wA + (mt * 16 + l15) * 64 + l4 * 8;
                h16x8 a0 = *(const h16x8*)(ap);
                h16x8 a1 = *(const h16x8*)(ap + 32);
                f32x4 a = (mt == 0) ? acc0 : (mt == 1) ? acc1
                        : (mt == 2) ? acc2 : acc3;
                a = __builtin_amdgcn_mfma_f32_16x16x32_f16(a0, bfP[cur][0], a, 0, 0, 0);
                a = __builtin_amdgcn_mfma_f32_16x16x32_f16(a1, bfP[cur][1], a, 0, 0, 0);
                if (mt == 0) acc0 = a; else if (mt == 1) acc1 = a;
                else if (mt == 2) acc2 = a; else acc3 = a;
            }
            _Float16* wl = wls + wv * 16 + l15;
#pragma unroll
            for (int mt = 0; mt < 4; ++mt) {
                f32x4 a = (mt == 0) ? acc0 : (mt == 1) ? acc1
                        : (mt == 2) ? acc2 : acc3;
#pragma unroll
                for (int r = 0; r < 4; ++r) {
                    int k = mt * 16 + l4 * 4 + r;
                    if (k < KK) wl[k * WSTR] = (_Float16)(a[r] + bg[k]);
                }
            }
        }

        // ---- bn2 params now (their vmcnt wait precedes prefetch issue) ----
        int c_out = g * GC + chB;
        float inv = g2v[c_out] * rsqrtf(var2[c_out] + 1e-5f);
        float off = be2[c_out] - mu2[c_out] * inv;

        // ---- issue next unit's loads (fly across B2 + phase B) ----
        if (u < 3) {
            int un2 = un + 1;
            int gN = un2 / 49, tileN = un2 % 49;
            int px0N = tileN * 64, h0N = px0N / HW;
            const _Float16* xpgN = xpad + ((size_t)b * NC + (size_t)gN * GC) * XPSLICE;
#pragma unroll
            for (int su = 0; su < 4; ++su) {
                int c_ = su * 256 + tid;
                int ch = c_ >> 6, rem = c_ & 63, rr = rem >> 3, c8 = rem & 7;
                xrP[nxt][su] = *(const h16x8*)(xpgN + (size_t)ch * XPSLICE
                                               + (h0N + rr) * XPW + c8 * 8);
            }
            int pxcN = px0N + wv * 16 + l15;
            const _Float16* tpN = tT + ((size_t)b * NPX + pxcN) * RED + l4 * 8;
            bfP[nxt][0] = *(const h16x8*)tpN;
            bfP[nxt][1] = *(const h16x8*)(tpN + 32);
        }

        // ---- B2: xtap + wls visible to all waves ----
        asm volatile("s_waitcnt lgkmcnt(0)" ::: "memory");
        __builtin_amdgcn_s_barrier();
        __builtin_amdgcn_sched_barrier(0);

        // ---- phase B: involution + bn2 + relu (LDS-only reads) ----
        int pxl  = quad * 4;
        int px_a = px0 + pxl;
        int lh   = px_a / HW - h0;         // 0 or 1
        int w0   = px_a % HW;              // multiple of 4

        const _Float16* xr0 = xtap + chB * XT_CS + lh * XT_RS + w0;
        float a0 = 0.f, a1 = 0.f, a2 = 0.f, a3 = 0.f;
#pragma unroll
        for (int i = 0; i < KS; ++i) {
            h16x4 t0 = *(const h16x4*)(xr0 + i * XT_RS);
            h16x4 t1 = *(const h16x4*)(xr0 + i * XT_RS + 4);
            h16x4 t2 = *(const h16x4*)(xr0 + i * XT_RS + 8);
            float cc[12];
            cc[0] = (float)t0[0]; cc[1]  = (float)t0[1]; cc[2]  = (float)t0[2]; cc[3]  = (float)t0[3];
            cc[4] = (float)t1[0]; cc[5]  = (float)t1[1]; cc[6]  = (float)t1[2]; cc[7]  = (float)t1[3];
            cc[8] = (float)t2[0]; cc[9]  = (float)t2[1]; cc[10] = (float)t2[2]; cc[11] = (float)t2[3];
#pragma unroll
            for (int j = 0; j < KS; ++j) {
                h16x4 wp = *(const h16x4*)&wls[(i * KS + j) * WSTR + pxl];
                a0 = fmaf((float)wp[0], cc[j + 0], a0);
                a1 = fmaf((float)wp[1], cc[j + 1], a1);
                a2 = fmaf((float)wp[2], cc[j + 2], a2);
                a3 = fmaf((float)wp[3], cc[j + 3], a3);
            }
        }

        f32x4 o;
        o[0] = fmaxf(a0 * inv + off, 0.0f);
        o[1] = fmaxf(a1 * inv + off, 0.0f);
        o[2] = fmaxf(a2 * inv + off, 0.0f);
        o[3] = fmaxf(a3 * inv + off, 0.0f);
        *(f32x4*)(out + ((size_t)b * NC + c_out) * NPX + px_a) = o;
    }
}

// ---------------------------------------------------------------------------
extern "C" void kernel_launch(void* const* d_in, const int* in_sizes, int n_in,
                              void* d_out, int out_size, void* d_ws, size_t ws_size,
                              hipStream_t stream) {
    const float* x    = (const float*)d_in[0];
    const float* w1   = (const float*)d_in[1];
    const float* g1   = (const float*)d_in[2];
    const float* be1  = (const float*)d_in[3];
    const float* mu1  = (const float*)d_in[4];
    const float* var1 = (const float*)d_in[5];
    const float* w2   = (const float*)d_in[6];
    const float* b2   = (const float*)d_in[7];
    const float* g2   = (const float*)d_in[8];
    const float* be2  = (const float*)d_in[9];
    const float* mu2  = (const float*)d_in[10];
    const float* var2 = (const float*)d_in[11];
    float* outp = (float*)d_out;

    // ws: xpad f16 16.3MB | tT f16 3.2MB | w2h 128KB | w1h 32KB
    _Float16* xpad = (_Float16*)d_ws;
    _Float16* tT   = xpad + (size_t)NB * NC * XPSLICE;
    _Float16* w2h  = tT + (size_t)NB * NPX * RED;
    _Float16* w1h  = w2h + (size_t)NG * 4096;

    prep_kernel<<<NB * NC + NG + 1, 256, 0, stream>>>(x, w1, w2, xpad, w1h, w2h);
    conv1_kernel<<<1568, 64, 0, stream>>>(xpad, w1h, g1, be1, mu1, var1, tT);
    involution_kernel<<<1568, 256, 0, stream>>>(
        xpad, tT, w2h, b2, g2, be2, mu2, var2, outp);
}

// Round 18
// 63.992 us; speedup vs baseline: 1.3404x; 1.1733x over previous
//
#include <hip/hip_runtime.h>
#include <hip/hip_fp16.h>

// Problem constants
#define NB   8
#define NC   256
#define HW   56
#define NPX  3136          // 56*56
#define RED  64
#define NG   16
#define GC   16
#define KS   7
#define KK   49
#define PADK 3
#define XPH  62            // padded rows: 3 + 56 + 3
#define XPW  64            // padded row stride (elements)
#define XPSLICE (XPH * XPW)   // 3968 f16 per channel slice
// K2 tiling
#define TPX  224           // px tile = 4 full pixel rows
#define NT2  14            // 3136 / 224
#define XT2_CS 644         // xtap ch stride (f16): 10*64+4 -> bank spread
#define WSTR2  232         // wls px stride (f16): 464 B, 16B-multiple

typedef float f32x4 __attribute__((ext_vector_type(4)));
typedef _Float16 h16x4 __attribute__((ext_vector_type(4)));
typedef _Float16 h16x8 __attribute__((ext_vector_type(8)));

// ---------------------------------------------------------------------------
// K0: fused prep.  blocks 0..2047: pad+convert x -> xpad f16, XCD-ALIGNED:
//     b = bid&7 so batch b's slices are written (and later read by conv1/K2,
//     which also pin b = XCD) entirely within one XCD's private L2.
//     blocks 2048..2063: w2 -> w2h f16; block 2064: w1 -> w1h.
// ---------------------------------------------------------------------------
__global__ __launch_bounds__(256) void prep_kernel(
    const float* __restrict__ x, const float* __restrict__ w1,
    const float* __restrict__ w2, _Float16* __restrict__ xpad,
    _Float16* __restrict__ w1h, _Float16* __restrict__ w2h) {
    int bid = blockIdx.x;
    if (bid < NB * NC) {
        int b = bid & 7, c = bid >> 3;         // XCD-aligned: batch = XCD
        const float* xs = x + ((size_t)b * NC + c) * NPX;
        _Float16* xd = xpad + ((size_t)b * NC + c) * XPSLICE;
#pragma unroll 4
        for (int e = threadIdx.x; e < XPSLICE; e += 256) {
            int row = e >> 6, col = e & 63;
            int h = row - PADK, w = col - PADK;
            float v = (h >= 0 && h < HW && w >= 0 && w < HW) ? xs[h * HW + w] : 0.0f;
            xd[e] = (_Float16)v;
        }
    } else if (bid < NB * NC + NG) {
        int g = bid - NB * NC;
#pragma unroll 4
        for (int e = threadIdx.x; e < 4096; e += 256) {
            int m = e >> 6, k = e & 63;
            float v = (m < KK) ? w2[((size_t)g * KK + m) * RED + k] : 0.0f;
            w2h[(size_t)g * 4096 + e] = (_Float16)v;
        }
    } else {
#pragma unroll 4
        for (int e = threadIdx.x; e < 64 * 256; e += 256)
            w1h[e] = (_Float16)w1[e];
    }
}

// ---------------------------------------------------------------------------
// K1: conv1 via MFMA f16 (r12/r15 version, 1 wave/block).
// Grid 1568 (8b x 196 nt; b = wgid&7 = XCD), 64 thr. Wave: C[64 o][16 px].
// Gathers now hit the local XCD L2 (xpad written by same XCD in prep).
// ---------------------------------------------------------------------------
__global__ __launch_bounds__(64) void conv1_kernel(
    const _Float16* __restrict__ xpad, const _Float16* __restrict__ w1h,
    const float* __restrict__ g1, const float* __restrict__ be1,
    const float* __restrict__ mu1, const float* __restrict__ var1,
    _Float16* __restrict__ tT) {
    int lane = threadIdx.x;
    int l15 = lane & 15, l4 = lane >> 4;
    int wgid = blockIdx.x;                 // 1568 = 8 * 196
    int b  = wgid & 7;                     // XCD-local batch
    int nt = wgid >> 3;                    // 0..195
    int px = nt * 16 + l15;
    int h = px / HW, w = px % HW;

    const _Float16* xp = xpad + (size_t)b * NC * XPSLICE
                       + (h + PADK) * XPW + (w + PADK);

    f32x4 acc0 = {0,0,0,0}, acc1 = {0,0,0,0}, acc2 = {0,0,0,0}, acc3 = {0,0,0,0};
#pragma unroll
    for (int kk = 0; kk < 8; ++kk) {
        h16x8 bfr;
#pragma unroll
        for (int i = 0; i < 8; ++i)
            bfr[i] = xp[(size_t)(kk * 32 + l4 * 8 + i) * XPSLICE];
#pragma unroll
        for (int mt = 0; mt < 4; ++mt) {
            const _Float16* ap = w1h + (mt * 16 + l15) * NC + kk * 32 + l4 * 8;
            h16x8 a = *(const h16x8*)ap;
            f32x4 c = (mt == 0) ? acc0 : (mt == 1) ? acc1 : (mt == 2) ? acc2 : acc3;
            c = __builtin_amdgcn_mfma_f32_16x16x32_f16(a, bfr, c, 0, 0, 0);
            if (mt == 0) acc0 = c; else if (mt == 1) acc1 = c;
            else if (mt == 2) acc2 = c; else acc3 = c;
        }
    }

    _Float16* tb = tT + ((size_t)b * NPX + px) * RED;
#pragma unroll
    for (int mt = 0; mt < 4; ++mt) {
        f32x4 a = (mt == 0) ? acc0 : (mt == 1) ? acc1 : (mt == 2) ? acc2 : acc3;
        int o0 = mt * 16 + l4 * 4;
        h16x4 pk;
#pragma unroll
        for (int r = 0; r < 4; ++r) {
            int o = o0 + r;
            float inv = g1[o] * rsqrtf(var1[o] + 1e-5f);
            float v = a[r] * inv + (be1[o] - mu1[o] * inv);
            pk[r] = (_Float16)fmaxf(v, 0.0f);
        }
        *(h16x4*)(tb + o0) = pk;
    }
}

// ---------------------------------------------------------------------------
// K2: fused conv2(MFMA f16) -> involution -> bn2 -> relu (r15 verbatim).
// Tile = 224 px (4 full rows) x 1 group. Grid 1792 (XCD-swizzled 8x224),
// block 448 = 7 waves. LDS: xtap (20.6 KB) + wls [49][232] (22.7 KB).
// ---------------------------------------------------------------------------
__global__ __launch_bounds__(448, 3) void involution_kernel(
    const _Float16* __restrict__ xpad, const _Float16* __restrict__ tT,
    const _Float16* __restrict__ w2h, const float* __restrict__ b2,
    const float* __restrict__ g2, const float* __restrict__ be2,
    const float* __restrict__ mu2, const float* __restrict__ var2,
    float* __restrict__ out) {
    __shared__ __align__(16) _Float16 xtap[GC * XT2_CS];  // 20,608 B
    __shared__ __align__(16) _Float16 wls[KK * WSTR2];    // 22,736 B

    int tid  = threadIdx.x;
    int lane = tid & 63;
    int wv   = __builtin_amdgcn_readfirstlane(tid >> 6);   // 0..6 SGPR
    int wgid = blockIdx.x;                 // 1792 = 8 * 224
    int swz  = (wgid & 7) * 224 + (wgid >> 3);
    int b    = swz / 224;
    int rem  = swz % 224;
    int g    = rem / NT2;                  // 0..15
    int tile = rem % NT2;                  // 0..13
    int px0 = tile * TPX;
    int R0  = tile * 4;                    // first output pixel-row

    const _Float16* xpg = xpad + ((size_t)b * NC + (size_t)g * GC) * XPSLICE;

    // ---- step 1 (T14): issue xtap staging loads (1280 16B-chunks) ----
    h16x8 xr[3];
#pragma unroll
    for (int u = 0; u < 3; ++u) {
        int cid = u * 448 + tid;
        if (cid < 1280) {
            int ch = cid / 80;             // 80 = 10 rows * 8 chunks
            int rm = cid % 80;
            int rr = rm >> 3, c8 = rm & 7;
            xr[u] = *(const h16x8*)(xpg + (size_t)ch * XPSLICE
                                    + (R0 + rr) * XPW + c8 * 8);
        }
    }

    // ---- step 2: phase A MFMA  wgt[49 x 224px] = w2h[49x64r] . tT[px][64r] ----
    {
        int l15 = lane & 15, l4 = lane >> 4;
        const _Float16* wA = w2h + (size_t)g * 4096;
        const float* bg = b2 + (size_t)g * KK;
        h16x8 a0[4], a1[4];
#pragma unroll
        for (int mt = 0; mt < 4; ++mt) {
            const _Float16* ap = wA + (mt * 16 + l15) * 64 + l4 * 8;
            a0[mt] = *(const h16x8*)(ap);
            a1[mt] = *(const h16x8*)(ap + 32);
        }
#pragma unroll
        for (int it = 0; it < 2; ++it) {
            int nt = wv * 2 + it;          // 0..13 (wave-uniform)
            int pxc = px0 + nt * 16 + l15;
            const _Float16* tp = tT + ((size_t)b * NPX + pxc) * RED + l4 * 8;
            h16x8 bfr0 = *(const h16x8*)tp;
            h16x8 bfr1 = *(const h16x8*)(tp + 32);

            f32x4 acc0 = {0,0,0,0}, acc1 = {0,0,0,0},
                  acc2 = {0,0,0,0}, acc3 = {0,0,0,0};
#pragma unroll
            for (int mt = 0; mt < 4; ++mt) {
                f32x4 a = (mt == 0) ? acc0 : (mt == 1) ? acc1
                        : (mt == 2) ? acc2 : acc3;
                a = __builtin_amdgcn_mfma_f32_16x16x32_f16(a0[mt], bfr0, a, 0, 0, 0);
                a = __builtin_amdgcn_mfma_f32_16x16x32_f16(a1[mt], bfr1, a, 0, 0, 0);
                if (mt == 0) acc0 = a; else if (mt == 1) acc1 = a;
                else if (mt == 2) acc2 = a; else acc3 = a;
            }
            _Float16* wl = wls + nt * 16 + l15;
#pragma unroll
            for (int mt = 0; mt < 4; ++mt) {
                f32x4 a = (mt == 0) ? acc0 : (mt == 1) ? acc1
                        : (mt == 2) ? acc2 : acc3;
#pragma unroll
                for (int r = 0; r < 4; ++r) {
                    int k = mt * 16 + l4 * 4 + r;
                    if (k < KK) wl[k * WSTR2] = (_Float16)(a[r] + bg[k]);
                }
            }
        }
    }

    // ---- step 3: write staged regs to LDS, ONE barrier ----
#pragma unroll
    for (int u = 0; u < 3; ++u) {
        int cid = u * 448 + tid;
        if (cid < 1280) {
            int ch = cid / 80;
            int rm = cid % 80;
            int rr = rm >> 3, c8 = rm & 7;
            *(h16x8*)&xtap[ch * XT2_CS + rr * 64 + c8 * 8] = xr[u];
        }
    }
    __syncthreads();

    // ---- step 4: phase B, thread = (octet, ch): 8 px x 1 ch ----
    int octet = tid >> 4;                  // 0..27
    int ch    = tid & 15;                  // 0..15
    int lin   = octet * 8;                 // 0..216
    int lh    = lin / 56;                  // 0..3
    int w0    = lin % 56;                  // multiple of 8

    const _Float16* xb0 = xtap + ch * XT2_CS + lh * 64 + w0;
    float acc[8];
#pragma unroll
    for (int p = 0; p < 8; ++p) acc[p] = 0.0f;

#pragma unroll
    for (int i = 0; i < KS; ++i) {
        h16x8 t0 = *(const h16x8*)(xb0 + i * 64);       // cols w0..w0+7
        h16x8 t1 = *(const h16x8*)(xb0 + i * 64 + 8);   // cols w0+8..w0+15
        float cc[16];
#pragma unroll
        for (int p = 0; p < 8; ++p) { cc[p] = (float)t0[p]; cc[8 + p] = (float)t1[p]; }
#pragma unroll
        for (int j = 0; j < KS; ++j) {
            h16x8 wq = *(const h16x8*)&wls[(i * KS + j) * WSTR2 + lin];
#pragma unroll
            for (int p = 0; p < 8; ++p)
                acc[p] = fmaf((float)wq[p], cc[j + p], acc[p]);
        }
    }

    int c_ = g * GC + ch;
    float inv = g2[c_] * rsqrtf(var2[c_] + 1e-5f);
    float off = be2[c_] - mu2[c_] * inv;
    float* op = out + ((size_t)b * NC + c_) * NPX + px0 + lin;
    f32x4 o0, o1;
#pragma unroll
    for (int p = 0; p < 4; ++p) {
        o0[p] = fmaxf(acc[p] * inv + off, 0.0f);
        o1[p] = fmaxf(acc[4 + p] * inv + off, 0.0f);
    }
    *(f32x4*)(op)     = o0;
    *(f32x4*)(op + 4) = o1;
}

// ---------------------------------------------------------------------------
extern "C" void kernel_launch(void* const* d_in, const int* in_sizes, int n_in,
                              void* d_out, int out_size, void* d_ws, size_t ws_size,
                              hipStream_t stream) {
    const float* x    = (const float*)d_in[0];
    const float* w1   = (const float*)d_in[1];
    const float* g1   = (const float*)d_in[2];
    const float* be1  = (const float*)d_in[3];
    const float* mu1  = (const float*)d_in[4];
    const float* var1 = (const float*)d_in[5];
    const float* w2   = (const float*)d_in[6];
    const float* b2   = (const float*)d_in[7];
    const float* g2   = (const float*)d_in[8];
    const float* be2  = (const float*)d_in[9];
    const float* mu2  = (const float*)d_in[10];
    const float* var2 = (const float*)d_in[11];
    float* outp = (float*)d_out;

    // ws: xpad f16 16.3MB | tT f16 3.2MB | w2h 128KB | w1h 32KB
    _Float16* xpad = (_Float16*)d_ws;
    _Float16* tT   = xpad + (size_t)NB * NC * XPSLICE;
    _Float16* w2h  = tT + (size_t)NB * NPX * RED;
    _Float16* w1h  = w2h + (size_t)NG * 4096;

    prep_kernel<<<NB * NC + NG + 1, 256, 0, stream>>>(x, w1, w2, xpad, w1h, w2h);
    conv1_kernel<<<1568, 64, 0, stream>>>(xpad, w1h, g1, be1, mu1, var1, tT);
    involution_kernel<<<1792, 448, 0, stream>>>(
        xpad, tT, w2h, b2, g2, be2, mu2, var2, outp);
}